// Round 6
// baseline (967.036 us; speedup 1.0000x reference)
//
#include <hip/hip_runtime.h>

#define NBIN 256
#define NREP 512                  // replicated global tables for img1 (L2-resident, 1 MB)
#define EPSF 1e-10f
#define DSCALE 4096.0f            // 2^12 fixed-point scale for fractional part
#define DSCALE_INV (1.0 / 4096.0)
#define DMASK ((1ull << 40) - 1)  // packed u64: count<<40 | fracsum(2^12)
#define CONE64 (1ull << 40)

// ---- monotone float<->uint encoding for atomicMin on floats ----
__device__ __forceinline__ unsigned enc_f32(float f) {
    unsigned u = __float_as_uint(f);
    return (u & 0x80000000u) ? ~u : (u ^ 0x80000000u);
}
__device__ __forceinline__ float dec_f32(unsigned e) {
    unsigned u = (e & 0x80000000u) ? (e ^ 0x80000000u) : ~e;
    return __uint_as_float(u);
}

// ws layout:
//   [byte 0]    encoded running min (unsigned)
//   [byte 16]   gh[512]  u64: [0..255]=img0 packed, [256..511]=img1 packed
//   [byte 16+4096] rep[NREP][NBIN] u64: per-replica img1 tables
__global__ void init_kernel(unsigned* ws_min, unsigned long long* gh,
                            unsigned long long* rep) {
    int t = blockIdx.x * blockDim.x + threadIdx.x;
    if (t == 0) *ws_min = 0xFFFFFFFFu;
    int total = NREP * NBIN;
    for (int j = t; j < 2 * NBIN; j += gridDim.x * blockDim.x) gh[j] = 0ull;
    for (int j = t; j < total; j += gridDim.x * blockDim.x) rep[j] = 0ull;
}

__global__ void __launch_bounds__(256) min_kernel(const float4* __restrict__ img0,
                                                  long n4, unsigned* ws_min) {
    long stride = (long)gridDim.x * blockDim.x;
    long i = (long)blockIdx.x * blockDim.x + threadIdx.x;
    float m = __int_as_float(0x7f800000);  // +inf
    if (i < n4) {
        float4 cur = img0[i];
        long j = i + stride;
        for (; j < n4; j += stride) {
            float4 nxt = img0[j];
            m = fminf(m, fminf(fminf(cur.x, cur.y), fminf(cur.z, cur.w)));
            cur = nxt;
        }
        m = fminf(m, fminf(fminf(cur.x, cur.y), fminf(cur.z, cur.w)));
    }
    for (int off = 32; off; off >>= 1) m = fminf(m, __shfl_xor(m, off));
    __shared__ float sm[4];
    int lane = threadIdx.x & 63, wid = threadIdx.x >> 6;
    if (lane == 0) sm[wid] = m;
    __syncthreads();
    if (threadIdx.x == 0) {
        float bm = fminf(fminf(sm[0], sm[1]), fminf(sm[2], sm[3]));
        atomicMin(ws_min, enc_f32(bm));
    }
}

// LDS path (img0): packed u32 (count<<24 | frac12), one ds_add per kept element
__device__ __forceinline__ void hadd_lds(float v, float hmin, float inv_dh,
                                         unsigned* h) {
    if (v >= hmin && v <= 0.f) {
        float x = (v - hmin) * inv_dh;
        float fi = floorf(x);
        int idx = (int)fi;                                  // 0..255
        unsigned di = __float2uint_rn((x - fi) * DSCALE);   // <= 4096
        atomicAdd(&h[idx], (1u << 24) | di);
    }
}

// Global/L2 path (img1): packed u64 (count<<40 | frac12) into a replica table.
// Runs on the TCC atomic units -> overlaps with the LDS pipe.
__device__ __forceinline__ void hadd_glb(float v, float hmin, float inv_dh,
                                         unsigned long long* t) {
    if (v >= hmin && v <= 0.f) {
        float x = (v - hmin) * inv_dh;
        float fi = floorf(x);
        int idx = (int)fi;
        unsigned di = __float2uint_rn((x - fi) * DSCALE);
        atomicAdd(&t[idx], CONE64 | (unsigned long long)di);
    }
}

__global__ void __launch_bounds__(256) hist_kernel(const float4* __restrict__ img0,
                                                   const float4* __restrict__ img1,
                                                   long n4, const unsigned* ws_min,
                                                   unsigned long long* __restrict__ gh,
                                                   unsigned long long* __restrict__ rep) {
    // img0: per-wave LDS tables (4 waves x 256 bins, packed u32) = 4 KB
    __shared__ unsigned lh[4][NBIN];
    int tid = threadIdx.x;
    int wid = tid >> 6;
    unsigned* base = &lh[0][0];
    for (int j = tid; j < 4 * NBIN; j += 256) base[j] = 0u;
    __syncthreads();

    float hmin = dec_f32(*ws_min);
    float dh = (0.f - hmin) / (NBIN - 1);
    float inv_dh = 1.0f / dh;

    long stride = (long)gridDim.x * blockDim.x;
    unsigned* h0 = &lh[wid][0];
    // img1 replica: 8192 waves spread over 512 tables (16 waves each)
    unsigned long long* t1 = &rep[(size_t)((blockIdx.x * 4 + wid) & (NREP - 1)) * NBIN];

    long i = (long)blockIdx.x * blockDim.x + tid;
    if (i < n4) {
        float4 a = img0[i];
        float4 b = img1[i];
        long j = i + stride;
        for (; j < n4; j += stride) {
            float4 an = img0[j];
            float4 bn = img1[j];
            hadd_lds(a.x, hmin, inv_dh, h0);
            hadd_lds(a.y, hmin, inv_dh, h0);
            hadd_lds(a.z, hmin, inv_dh, h0);
            hadd_lds(a.w, hmin, inv_dh, h0);
            hadd_glb(b.x, hmin, inv_dh, t1);
            hadd_glb(b.y, hmin, inv_dh, t1);
            hadd_glb(b.z, hmin, inv_dh, t1);
            hadd_glb(b.w, hmin, inv_dh, t1);
            a = an;
            b = bn;
        }
        hadd_lds(a.x, hmin, inv_dh, h0);
        hadd_lds(a.y, hmin, inv_dh, h0);
        hadd_lds(a.z, hmin, inv_dh, h0);
        hadd_lds(a.w, hmin, inv_dh, h0);
        hadd_glb(b.x, hmin, inv_dh, t1);
        hadd_glb(b.y, hmin, inv_dh, t1);
        hadd_glb(b.z, hmin, inv_dh, t1);
        hadd_glb(b.w, hmin, inv_dh, t1);
    }
    __syncthreads();

    // merge img0's 4 wave copies, one u64 atomic per bin
    for (int b = tid; b < NBIN; b += 256) {
        unsigned long long c0 = 0, f0 = 0;
        for (int w = 0; w < 4; ++w) {
            unsigned p = lh[w][b];
            c0 += p >> 24;
            f0 += p & 0xFFFFFFu;
        }
        atomicAdd(&gh[b], (c0 << 40) | f0);
    }
}

// fold the 512 img1 replicas into gh[256..511]; packed fields can't overflow
// (total count/bin < 2^24, total frac/bin < 2^40)
__global__ void __launch_bounds__(256) reduce_kernel(const unsigned long long* __restrict__ rep,
                                                     unsigned long long* __restrict__ gh) {
    int t = blockIdx.x * blockDim.x + threadIdx.x;  // 0..4095
    int b = t & (NBIN - 1);
    int r0 = (t >> 8) * (NREP / 16);
    unsigned long long s = 0;
    for (int r = r0; r < r0 + NREP / 16; ++r) s += rep[(size_t)r * NBIN + b];
    atomicAdd(&gh[NBIN + b], s);
}

__global__ void __launch_bounds__(256) kl_kernel(const unsigned long long* __restrict__ gh,
                                                 float* __restrict__ out) {
    int i = threadIdx.x;  // exactly 256 threads, one bin each
    // unpack: h[b] = count[b] - dsum[b] + dsum[b-1]   (spill past 255 drops out)
    unsigned long long p0 = gh[i];
    unsigned long long p1 = gh[NBIN + i];
    unsigned long long q0 = (i > 0) ? gh[i - 1] : 0ull;
    unsigned long long q1 = (i > 0) ? gh[NBIN + i - 1] : 0ull;
    float h0 = (float)((double)(p0 >> 40) - (double)(p0 & DMASK) * DSCALE_INV
                       + (double)(q0 & DMASK) * DSCALE_INV);
    float h1 = (float)((double)(p1 >> 40) - (double)(p1 & DMASK) * DSCALE_INV
                       + (double)(q1 & DMASK) * DSCALE_INV);

    __shared__ float sw[4];
    int lane = i & 63, wid = i >> 6;

    float v = h0;
    for (int off = 32; off; off >>= 1) v += __shfl_xor(v, off);
    if (lane == 0) sw[wid] = v;
    __syncthreads();
    float s0 = sw[0] + sw[1] + sw[2] + sw[3];
    __syncthreads();

    v = h1;
    for (int off = 32; off; off >>= 1) v += __shfl_xor(v, off);
    if (lane == 0) sw[wid] = v;
    __syncthreads();
    float s1 = sw[0] + sw[1] + sw[2] + sw[3];
    __syncthreads();

    float a = (h0 + EPSF) / (s0 + EPSF);
    float b = (h1 + EPSF) / (s1 + EPSF);
    float tgt = logf((b + EPSF) / a);
    float inp = logf((b + EPSF) / b);
    float term = expf(tgt) * (tgt - inp);

    v = term;
    for (int off = 32; off; off >>= 1) v += __shfl_xor(v, off);
    if (lane == 0) sw[wid] = v;
    __syncthreads();
    if (i == 0) out[0] = (sw[0] + sw[1] + sw[2] + sw[3]) / (float)NBIN;
}

extern "C" void kernel_launch(void* const* d_in, const int* in_sizes, int n_in,
                              void* d_out, int out_size, void* d_ws, size_t ws_size,
                              hipStream_t stream) {
    const float* img0 = (const float*)d_in[0];
    const float* img1 = (const float*)d_in[1];
    float* out = (float*)d_out;
    unsigned* ws_min = (unsigned*)d_ws;
    unsigned long long* gh = (unsigned long long*)((char*)d_ws + 16);
    unsigned long long* rep = (unsigned long long*)((char*)d_ws + 16 + 4096);

    long n = (long)in_sizes[0];  // 67,108,864
    long n4 = n / 4;

    init_kernel<<<64, 256, 0, stream>>>(ws_min, gh, rep);
    min_kernel<<<2048, 256, 0, stream>>>((const float4*)img0, n4, ws_min);
    hist_kernel<<<2048, 256, 0, stream>>>((const float4*)img0, (const float4*)img1,
                                          n4, ws_min, gh, rep);
    reduce_kernel<<<16, 256, 0, stream>>>(rep, gh);
    kl_kernel<<<1, 256, 0, stream>>>(gh, out);
}

// Round 7
// 431.583 us; speedup vs baseline: 2.2407x; 2.2407x over previous
//
#include <hip/hip_runtime.h>

#define NBIN 256
#define NCOL 64                   // one column per 4-lane quad: 64 quads/block
#define EPSF 1e-10f
#define DSCALE 4096.0f            // 2^12 fixed-point scale for fractional part
#define DSCALE_INV (1.0 / 4096.0)
#define DMASK ((1ull << 40) - 1)  // global packed: count<<40 | fracsum(2^12)

// ---- monotone float<->uint encoding for atomicMin on floats ----
__device__ __forceinline__ unsigned enc_f32(float f) {
    unsigned u = __float_as_uint(f);
    return (u & 0x80000000u) ? ~u : (u ^ 0x80000000u);
}
__device__ __forceinline__ float dec_f32(unsigned e) {
    unsigned u = (e & 0x80000000u) ? (e ^ 0x80000000u) : ~e;
    return __uint_as_float(u);
}

__global__ void init_kernel(unsigned* ws_min, unsigned long long* gh) {
    if (threadIdx.x == 0 && blockIdx.x == 0) *ws_min = 0xFFFFFFFFu;
    int t = blockIdx.x * blockDim.x + threadIdx.x;
    for (int j = t; j < 2 * NBIN; j += gridDim.x * blockDim.x) gh[j] = 0ull;
}

__global__ void __launch_bounds__(256) min_kernel(const float4* __restrict__ img0,
                                                  long n4, unsigned* ws_min) {
    long stride = (long)gridDim.x * blockDim.x;
    long i = (long)blockIdx.x * blockDim.x + threadIdx.x;
    float m = __int_as_float(0x7f800000);  // +inf
    if (i < n4) {
        float4 cur = img0[i];
        long j = i + stride;
        for (; j < n4; j += stride) {
            float4 nxt = img0[j];
            m = fminf(m, fminf(fminf(cur.x, cur.y), fminf(cur.z, cur.w)));
            cur = nxt;
        }
        m = fminf(m, fminf(fminf(cur.x, cur.y), fminf(cur.z, cur.w)));
    }
    for (int off = 32; off; off >>= 1) m = fminf(m, __shfl_xor(m, off));
    __shared__ float sm[4];
    int lane = threadIdx.x & 63, wid = threadIdx.x >> 6;
    if (lane == 0) sm[wid] = m;
    __syncthreads();
    if (threadIdx.x == 0) {
        float bm = fminf(fminf(sm[0], sm[1]), fminf(sm[2], sm[3]));
        atomicMin(ws_min, enc_f32(bm));
    }
}

// Non-atomic RMW histogram update. Each 4-lane quad owns an exclusive column;
// within-quad same-bin collisions are merged exactly in registers via DPP
// quad_perm exchanges (VALU pipe), then only the leader lane does the
// ds_read+add+ds_write. Dropped lanes carry pv=0 (harmless even as leader).
__device__ __forceinline__ void hrmw(float v, float hmin, float inv_dh,
                                     unsigned* tab, int lpos) {
    bool keep = (v >= hmin) && (v <= 0.f);
    float x = (v - hmin) * inv_dh;
    x = fminf(fmaxf(x, 0.f), 255.f);         // clamp (also covers dropped lanes)
    float fi = floorf(x);
    int idx = (int)fi;
    unsigned di = __float2uint_rn((x - fi) * DSCALE);        // <= 4096
    unsigned pv = keep ? ((1u << 22) | di) : 0u;             // count<<22 | frac

    // quad_perm exchanges: partner = lane position ^1, ^2, ^3
    int i1 = __builtin_amdgcn_update_dpp(0, idx, 0xB1, 0xF, 0xF, true);
    int p1 = __builtin_amdgcn_update_dpp(0, (int)pv, 0xB1, 0xF, 0xF, true);
    int i2 = __builtin_amdgcn_update_dpp(0, idx, 0x4E, 0xF, 0xF, true);
    int p2 = __builtin_amdgcn_update_dpp(0, (int)pv, 0x4E, 0xF, 0xF, true);
    int i3 = __builtin_amdgcn_update_dpp(0, idx, 0x1B, 0xF, 0xF, true);
    int p3 = __builtin_amdgcn_update_dpp(0, (int)pv, 0x1B, 0xF, 0xF, true);
    bool eq1 = (idx == i1), eq2 = (idx == i2), eq3 = (idx == i3);
    unsigned tot = pv + (eq1 ? (unsigned)p1 : 0u)
                      + (eq2 ? (unsigned)p2 : 0u)
                      + (eq3 ? (unsigned)p3 : 0u);
    // leader = lowest quad-position among equal-idx lanes
    bool notldr = (eq1 && (lpos & 1)) || ((eq2 || eq3) && (lpos & 2));
    if (!notldr) tab[idx] += tot;            // exclusive column: plain RMW
}

__global__ void __launch_bounds__(256) hist_kernel(const float4* __restrict__ img0,
                                                   const float4* __restrict__ img1,
                                                   long n4, const unsigned* ws_min,
                                                   unsigned long long* __restrict__ gh) {
    // per-quad columns: [img][col][bin] u32 packed (count<<22 | fracsum12)
    // addr%32 banks = idx%32 -> lanes spread by bin, ~2-way worst (free)
    __shared__ unsigned lh[2][NCOL][NBIN];
    int tid = threadIdx.x;
    int col = tid >> 2;          // 64 quads per 256-thread block
    int lpos = tid & 3;
    unsigned* base = &lh[0][0][0];
    for (int j = tid; j < 2 * NCOL * NBIN; j += 256) base[j] = 0u;
    __syncthreads();

    float hmin = dec_f32(*ws_min);
    float dh = (0.f - hmin) / (NBIN - 1);
    float inv_dh = 1.0f / dh;

    unsigned* t0 = &lh[0][col][0];
    unsigned* t1 = &lh[1][col][0];

    long stride = (long)gridDim.x * blockDim.x;
    long i = (long)blockIdx.x * blockDim.x + tid;

    // depth-2 software prefetch: ~2 iterations of loads in flight
    float4 ac, bc, an, bn;
    if (i < n4) { ac = img0[i]; bc = img1[i]; }
    if (i + stride < n4) { an = img0[i + stride]; bn = img1[i + stride]; }
    for (; i < n4; i += stride) {
        long ipp = i + 2 * stride;
        float4 ap, bp;
        bool has = ipp < n4;
        if (has) { ap = img0[ipp]; bp = img1[ipp]; }
        hrmw(ac.x, hmin, inv_dh, t0, lpos);
        hrmw(ac.y, hmin, inv_dh, t0, lpos);
        hrmw(ac.z, hmin, inv_dh, t0, lpos);
        hrmw(ac.w, hmin, inv_dh, t0, lpos);
        hrmw(bc.x, hmin, inv_dh, t1, lpos);
        hrmw(bc.y, hmin, inv_dh, t1, lpos);
        hrmw(bc.z, hmin, inv_dh, t1, lpos);
        hrmw(bc.w, hmin, inv_dh, t1, lpos);
        ac = an; bc = bn;
        an = ap; bn = bp;
    }
    __syncthreads();

    // fold 64 columns per (img,bin); one global u64 atomic per pair per block
    for (int p = tid; p < 2 * NBIN; p += 256) {
        int im = p >> 8, b = p & 255;
        unsigned long long c = 0, f = 0;
        for (int cidx = 0; cidx < NCOL; ++cidx) {
            unsigned u = lh[im][cidx][b];
            c += u >> 22;
            f += u & 0x3FFFFFu;
        }
        atomicAdd(&gh[im * NBIN + b], (c << 40) | f);
    }
}

__global__ void __launch_bounds__(256) kl_kernel(const unsigned long long* __restrict__ gh,
                                                 float* __restrict__ out) {
    int i = threadIdx.x;  // exactly 256 threads, one bin each
    // unpack: h[b] = count[b] - dsum[b] + dsum[b-1]   (spill past 255 drops out)
    unsigned long long p0 = gh[i];
    unsigned long long p1 = gh[NBIN + i];
    unsigned long long q0 = (i > 0) ? gh[i - 1] : 0ull;
    unsigned long long q1 = (i > 0) ? gh[NBIN + i - 1] : 0ull;
    float h0 = (float)((double)(p0 >> 40) - (double)(p0 & DMASK) * DSCALE_INV
                       + (double)(q0 & DMASK) * DSCALE_INV);
    float h1 = (float)((double)(p1 >> 40) - (double)(p1 & DMASK) * DSCALE_INV
                       + (double)(q1 & DMASK) * DSCALE_INV);

    __shared__ float sw[4];
    int lane = i & 63, wid = i >> 6;

    float v = h0;
    for (int off = 32; off; off >>= 1) v += __shfl_xor(v, off);
    if (lane == 0) sw[wid] = v;
    __syncthreads();
    float s0 = sw[0] + sw[1] + sw[2] + sw[3];
    __syncthreads();

    v = h1;
    for (int off = 32; off; off >>= 1) v += __shfl_xor(v, off);
    if (lane == 0) sw[wid] = v;
    __syncthreads();
    float s1 = sw[0] + sw[1] + sw[2] + sw[3];
    __syncthreads();

    float a = (h0 + EPSF) / (s0 + EPSF);
    float b = (h1 + EPSF) / (s1 + EPSF);
    float tgt = logf((b + EPSF) / a);
    float inp = logf((b + EPSF) / b);
    float term = expf(tgt) * (tgt - inp);

    v = term;
    for (int off = 32; off; off >>= 1) v += __shfl_xor(v, off);
    if (lane == 0) sw[wid] = v;
    __syncthreads();
    if (i == 0) out[0] = (sw[0] + sw[1] + sw[2] + sw[3]) / (float)NBIN;
}

extern "C" void kernel_launch(void* const* d_in, const int* in_sizes, int n_in,
                              void* d_out, int out_size, void* d_ws, size_t ws_size,
                              hipStream_t stream) {
    const float* img0 = (const float*)d_in[0];
    const float* img1 = (const float*)d_in[1];
    float* out = (float*)d_out;
    unsigned* ws_min = (unsigned*)d_ws;
    unsigned long long* gh = (unsigned long long*)((char*)d_ws + 16);

    long n = (long)in_sizes[0];  // 67,108,864
    long n4 = n / 4;

    init_kernel<<<4, 256, 0, stream>>>(ws_min, gh);
    min_kernel<<<2048, 256, 0, stream>>>((const float4*)img0, n4, ws_min);
    hist_kernel<<<256, 256, 0, stream>>>((const float4*)img0, (const float4*)img1,
                                         n4, ws_min, gh);
    kl_kernel<<<1, 256, 0, stream>>>(gh, out);
}

// Round 8
// 197.208 us; speedup vs baseline: 4.9036x; 2.1885x over previous
//
#include <hip/hip_runtime.h>

#define NBIN 256
#define EPSF 1e-10f
#define DSCALE 4096.0f            // 2^12 fixed-point scale for fractional part
#define DSCALE_INV (1.0 / 4096.0)
#define DMASK ((1ull << 40) - 1)  // global packed: count<<40 | fracsum(2^12)

// ---- monotone float<->uint encoding for atomicMin on floats ----
__device__ __forceinline__ unsigned enc_f32(float f) {
    unsigned u = __float_as_uint(f);
    return (u & 0x80000000u) ? ~u : (u ^ 0x80000000u);
}
__device__ __forceinline__ float dec_f32(unsigned e) {
    unsigned u = (e & 0x80000000u) ? (e ^ 0x80000000u) : ~e;
    return __uint_as_float(u);
}

// ws layout: [0] = encoded running min (unsigned); u64 at byte offset 16:
//   gh[0..255]   = packed (count<<40 | dsum_fix12) for img0
//   gh[256..511] = same for img1
__global__ void init_kernel(unsigned* ws_min, unsigned long long* gh) {
    if (threadIdx.x == 0) *ws_min = 0xFFFFFFFFu;
    for (int j = threadIdx.x; j < 2 * NBIN; j += blockDim.x) gh[j] = 0ull;
}

__global__ void __launch_bounds__(256) min_kernel(const float4* __restrict__ img0,
                                                  long n4, unsigned* ws_min) {
    long stride = (long)gridDim.x * blockDim.x;
    long i = (long)blockIdx.x * blockDim.x + threadIdx.x;
    float m = __int_as_float(0x7f800000);  // +inf
    if (i < n4) {
        float4 cur = img0[i];
        long j = i + stride;
        for (; j < n4; j += stride) {
            float4 nxt = img0[j];
            m = fminf(m, fminf(fminf(cur.x, cur.y), fminf(cur.z, cur.w)));
            cur = nxt;
        }
        m = fminf(m, fminf(fminf(cur.x, cur.y), fminf(cur.z, cur.w)));
    }
    for (int off = 32; off; off >>= 1) m = fminf(m, __shfl_xor(m, off));
    __shared__ float sm[4];
    int lane = threadIdx.x & 63, wid = threadIdx.x >> 6;
    if (lane == 0) sm[wid] = m;
    __syncthreads();
    if (threadIdx.x == 0) {
        float bm = fminf(fminf(sm[0], sm[1]), fminf(sm[2], sm[3]));
        atomicMin(ws_min, enc_f32(bm));
    }
}

// BRANCHLESS histogram update: the atomic issues unconditionally (no
// s_and_saveexec / s_cbranch per update). Dropped lanes contribute pv=0 at a
// per-lane dummy address (64 distinct addresses, 2-way bank alias = free).
__device__ __forceinline__ void hadd(float v, float hmin, float inv_dh,
                                     unsigned* h, int lane) {
    bool keep = (v >= hmin) & (v <= 0.f);
    float x = (v - hmin) * inv_dh;
    x = fminf(fmaxf(x, 0.f), 255.f);          // safe for out-of-range lanes
    float fi = floorf(x);
    int idx = (int)fi;                         // 0..255
    unsigned di = __float2uint_rn((x - fi) * DSCALE);   // <= 4096
    unsigned pv = keep ? ((1u << 24) | di) : 0u;        // count<<24 | frac12
    idx = keep ? idx : lane;                   // value-neutral spread address
    atomicAdd(&h[idx], pv);
}

__global__ void __launch_bounds__(256) hist_kernel(const float4* __restrict__ img0,
                                                   const float4* __restrict__ img1,
                                                   long n4, const unsigned* ws_min,
                                                   unsigned long long* __restrict__ gh) {
    // per-wave privatized packed u32 histograms: 4 waves x 2 images x 256 bins = 8 KB
    __shared__ unsigned lh[4][2][NBIN];
    int tid = threadIdx.x;
    int wid = tid >> 6;
    int lane = tid & 63;
    unsigned* base = &lh[0][0][0];
    for (int j = tid; j < 4 * 2 * NBIN; j += 256) base[j] = 0u;
    __syncthreads();

    float hmin = dec_f32(*ws_min);
    float dh = (0.f - hmin) / (NBIN - 1);
    float inv_dh = 1.0f / dh;

    long stride = (long)gridDim.x * blockDim.x;
    unsigned* h0 = &lh[wid][0][0];
    unsigned* h1 = &lh[wid][1][0];

    long i = (long)blockIdx.x * blockDim.x + tid;
    if (i < n4) {
        float4 a = img0[i];
        float4 b = img1[i];
        long j = i + stride;
        for (; j < n4; j += stride) {
            float4 an = img0[j];
            float4 bn = img1[j];
            hadd(a.x, hmin, inv_dh, h0, lane);
            hadd(a.y, hmin, inv_dh, h0, lane);
            hadd(a.z, hmin, inv_dh, h0, lane);
            hadd(a.w, hmin, inv_dh, h0, lane);
            hadd(b.x, hmin, inv_dh, h1, lane);
            hadd(b.y, hmin, inv_dh, h1, lane);
            hadd(b.z, hmin, inv_dh, h1, lane);
            hadd(b.w, hmin, inv_dh, h1, lane);
            a = an;
            b = bn;
        }
        hadd(a.x, hmin, inv_dh, h0, lane);
        hadd(a.y, hmin, inv_dh, h0, lane);
        hadd(a.z, hmin, inv_dh, h0, lane);
        hadd(a.w, hmin, inv_dh, h0, lane);
        hadd(b.x, hmin, inv_dh, h1, lane);
        hadd(b.y, hmin, inv_dh, h1, lane);
        hadd(b.z, hmin, inv_dh, h1, lane);
        hadd(b.w, hmin, inv_dh, h1, lane);
    }
    __syncthreads();

    // merge the 4 wave copies (exact integer adds), one global u64 atomic per bin
    for (int b = tid; b < NBIN; b += 256) {
        unsigned long long c0 = 0, f0 = 0, c1 = 0, f1 = 0;
        for (int w = 0; w < 4; ++w) {
            unsigned p0 = lh[w][0][b];
            unsigned p1 = lh[w][1][b];
            c0 += p0 >> 24; f0 += p0 & 0xFFFFFFu;
            c1 += p1 >> 24; f1 += p1 & 0xFFFFFFu;
        }
        atomicAdd(&gh[b], (c0 << 40) | f0);
        atomicAdd(&gh[NBIN + b], (c1 << 40) | f1);
    }
}

__global__ void __launch_bounds__(256) kl_kernel(const unsigned long long* __restrict__ gh,
                                                 float* __restrict__ out) {
    int i = threadIdx.x;  // exactly 256 threads, one bin each
    // unpack: h[b] = count[b] - dsum[b] + dsum[b-1]   (spill past 255 drops out)
    unsigned long long p0 = gh[i];
    unsigned long long p1 = gh[NBIN + i];
    unsigned long long q0 = (i > 0) ? gh[i - 1] : 0ull;
    unsigned long long q1 = (i > 0) ? gh[NBIN + i - 1] : 0ull;
    float h0 = (float)((double)(p0 >> 40) - (double)(p0 & DMASK) * DSCALE_INV
                       + (double)(q0 & DMASK) * DSCALE_INV);
    float h1 = (float)((double)(p1 >> 40) - (double)(p1 & DMASK) * DSCALE_INV
                       + (double)(q1 & DMASK) * DSCALE_INV);

    __shared__ float sw[4];
    int lane = i & 63, wid = i >> 6;

    float v = h0;
    for (int off = 32; off; off >>= 1) v += __shfl_xor(v, off);
    if (lane == 0) sw[wid] = v;
    __syncthreads();
    float s0 = sw[0] + sw[1] + sw[2] + sw[3];
    __syncthreads();

    v = h1;
    for (int off = 32; off; off >>= 1) v += __shfl_xor(v, off);
    if (lane == 0) sw[wid] = v;
    __syncthreads();
    float s1 = sw[0] + sw[1] + sw[2] + sw[3];
    __syncthreads();

    float a = (h0 + EPSF) / (s0 + EPSF);
    float b = (h1 + EPSF) / (s1 + EPSF);
    float tgt = logf((b + EPSF) / a);
    float inp = logf((b + EPSF) / b);
    float term = expf(tgt) * (tgt - inp);

    v = term;
    for (int off = 32; off; off >>= 1) v += __shfl_xor(v, off);
    if (lane == 0) sw[wid] = v;
    __syncthreads();
    if (i == 0) out[0] = (sw[0] + sw[1] + sw[2] + sw[3]) / (float)NBIN;
}

extern "C" void kernel_launch(void* const* d_in, const int* in_sizes, int n_in,
                              void* d_out, int out_size, void* d_ws, size_t ws_size,
                              hipStream_t stream) {
    const float* img0 = (const float*)d_in[0];
    const float* img1 = (const float*)d_in[1];
    float* out = (float*)d_out;
    unsigned* ws_min = (unsigned*)d_ws;
    unsigned long long* gh = (unsigned long long*)((char*)d_ws + 16);

    long n = (long)in_sizes[0];  // 67,108,864
    long n4 = n / 4;

    init_kernel<<<1, 256, 0, stream>>>(ws_min, gh);
    min_kernel<<<2048, 256, 0, stream>>>((const float4*)img0, n4, ws_min);
    hist_kernel<<<2048, 256, 0, stream>>>((const float4*)img0, (const float4*)img1,
                                          n4, ws_min, gh);
    kl_kernel<<<1, 256, 0, stream>>>(gh, out);
}

// Round 9
// 180.752 us; speedup vs baseline: 5.3501x; 1.0910x over previous
//
#include <hip/hip_runtime.h>

#define NBIN 256
#define EPSF 1e-10f
#define DSCALE 4096.0f            // 2^12 fixed-point scale for fractional part
#define DSCALE_INV (1.0 / 4096.0)
#define DMASK ((1ull << 40) - 1)  // global packed: count<<40 | fracsum(2^12)
#define FULLM 0xFFFFFFFFFFFFFFFFull

// ---- monotone float<->uint encoding for atomicMin on floats ----
__device__ __forceinline__ unsigned enc_f32(float f) {
    unsigned u = __float_as_uint(f);
    return (u & 0x80000000u) ? ~u : (u ^ 0x80000000u);
}
__device__ __forceinline__ float dec_f32(unsigned e) {
    unsigned u = (e & 0x80000000u) ? (e ^ 0x80000000u) : ~e;
    return __uint_as_float(u);
}

// ws layout: [0] = encoded running min (unsigned); u64 at byte offset 16:
//   gh[0..255]   = packed (count<<40 | dsum_fix12) for img0
//   gh[256..511] = same for img1
__global__ void init_kernel(unsigned* ws_min, unsigned long long* gh) {
    if (threadIdx.x == 0) *ws_min = 0xFFFFFFFFu;
    for (int j = threadIdx.x; j < 2 * NBIN; j += blockDim.x) gh[j] = 0ull;
}

__global__ void __launch_bounds__(256) min_kernel(const float4* __restrict__ img0,
                                                  long n4, unsigned* ws_min) {
    long stride = (long)gridDim.x * blockDim.x;
    long i = (long)blockIdx.x * blockDim.x + threadIdx.x;
    float m = __int_as_float(0x7f800000);  // +inf
    if (i < n4) {
        float4 cur = img0[i];
        long j = i + stride;
        for (; j < n4; j += stride) {
            float4 nxt = img0[j];
            m = fminf(m, fminf(fminf(cur.x, cur.y), fminf(cur.z, cur.w)));
            cur = nxt;
        }
        m = fminf(m, fminf(fminf(cur.x, cur.y), fminf(cur.z, cur.w)));
    }
    for (int off = 32; off; off >>= 1) m = fminf(m, __shfl_xor(m, off));
    __shared__ float sm[4];
    int lane = threadIdx.x & 63, wid = threadIdx.x >> 6;
    if (lane == 0) sm[wid] = m;
    __syncthreads();
    if (threadIdx.x == 0) {
        float bm = fminf(fminf(sm[0], sm[1]), fminf(sm[2], sm[3]));
        atomicMin(ws_min, enc_f32(bm));
    }
}

// FIFO-batched histogram update. Each lane buffers up to 3 kept entries
// (21 bits each: (img<<8|idx)<<12 | frac12) in a u64 shift register. The wave
// issues ONE ds-atomic wave-instruction only when every lane has something to
// write (full utilization) or a lane is about to overflow. DS atomic cost is
// flat ~43 cyc/instruction (rounds 3/4/5/8 evidence), so fewer instructions
// is the only lever; target ~0.55 issues/slot instead of 1.0.
__device__ __forceinline__ void fifo_issue(unsigned* tab, int lane,
                                           unsigned long long& q, int& cnt) {
    bool has = cnt > 0;
    int sh = has ? 21 * (cnt - 1) : 0;
    unsigned e = has ? (unsigned)((q >> sh) & 0x1FFFFFull) : 0u;
    unsigned off = has ? (e >> 12) : (unsigned)lane;  // dummy: pv=0 at bin[lane]
    unsigned pv = has ? ((1u << 24) | (e & 0xFFFu)) : 0u;
    atomicAdd(&tab[off], pv);
    cnt -= has ? 1 : 0;
}

__device__ __forceinline__ void slot(float v, float hmin, float inv_dh, int img,
                                     unsigned* tab, int lane,
                                     unsigned long long& q, int& cnt) {
    bool keep = (v >= hmin) & (v <= 0.f);
    float x = (v - hmin) * inv_dh;
    x = fminf(fmaxf(x, 0.f), 255.f);
    float fi = floorf(x);
    int idx = (int)fi;                                   // 0..255
    unsigned di = __float2uint_rn((x - fi) * DSCALE);
    di = di > 4095u ? 4095u : di;                        // keep frac in 12 bits
    unsigned entry = ((unsigned)((img << 8) | idx) << 12) | di;  // 21 bits

    bool pressure = keep && (cnt == 3);
    unsigned long long ne = __ballot(cnt > 0);
    if (__ballot(pressure) != 0ull || ne == FULLM) {
        fifo_issue(tab, lane, q, cnt);                   // pops 1 where cnt>0
    }
    q = keep ? ((q << 21) | (unsigned long long)entry) : q;
    cnt += keep ? 1 : 0;
}

__global__ void __launch_bounds__(256) hist_kernel(const float4* __restrict__ img0,
                                                   const float4* __restrict__ img1,
                                                   long n4, const unsigned* ws_min,
                                                   unsigned long long* __restrict__ gh) {
    // per-wave privatized packed u32 tables: 4 waves x 2 images x 256 bins = 8 KB
    __shared__ unsigned lh[4][2][NBIN];
    int tid = threadIdx.x;
    int wid = tid >> 6;
    int lane = tid & 63;
    unsigned* base = &lh[0][0][0];
    for (int j = tid; j < 4 * 2 * NBIN; j += 256) base[j] = 0u;
    __syncthreads();

    float hmin = dec_f32(*ws_min);
    float dh = (0.f - hmin) / (NBIN - 1);
    float inv_dh = 1.0f / dh;

    long stride = (long)gridDim.x * blockDim.x;
    unsigned* tab = &lh[wid][0][0];   // flat [2][256]; entry off = img*256+idx

    unsigned long long q = 0ull;
    int cnt = 0;

    long i = (long)blockIdx.x * blockDim.x + tid;
    if (i < n4) {
        float4 a = img0[i];
        float4 b = img1[i];
        long j = i + stride;
        for (; j < n4; j += stride) {
            float4 an = img0[j];
            float4 bn = img1[j];
            slot(a.x, hmin, inv_dh, 0, tab, lane, q, cnt);
            slot(a.y, hmin, inv_dh, 0, tab, lane, q, cnt);
            slot(a.z, hmin, inv_dh, 0, tab, lane, q, cnt);
            slot(a.w, hmin, inv_dh, 0, tab, lane, q, cnt);
            slot(b.x, hmin, inv_dh, 1, tab, lane, q, cnt);
            slot(b.y, hmin, inv_dh, 1, tab, lane, q, cnt);
            slot(b.z, hmin, inv_dh, 1, tab, lane, q, cnt);
            slot(b.w, hmin, inv_dh, 1, tab, lane, q, cnt);
            a = an;
            b = bn;
        }
        slot(a.x, hmin, inv_dh, 0, tab, lane, q, cnt);
        slot(a.y, hmin, inv_dh, 0, tab, lane, q, cnt);
        slot(a.z, hmin, inv_dh, 0, tab, lane, q, cnt);
        slot(a.w, hmin, inv_dh, 0, tab, lane, q, cnt);
        slot(b.x, hmin, inv_dh, 1, tab, lane, q, cnt);
        slot(b.y, hmin, inv_dh, 1, tab, lane, q, cnt);
        slot(b.z, hmin, inv_dh, 1, tab, lane, q, cnt);
        slot(b.w, hmin, inv_dh, 1, tab, lane, q, cnt);
    }
    // drain remaining buffered entries (depth <= 3)
    for (int k = 0; k < 3; ++k) fifo_issue(tab, lane, q, cnt);
    __syncthreads();

    // merge the 4 wave copies (exact integer adds), one global u64 atomic per bin
    for (int b = tid; b < NBIN; b += 256) {
        unsigned long long c0 = 0, f0 = 0, c1 = 0, f1 = 0;
        for (int w = 0; w < 4; ++w) {
            unsigned p0 = lh[w][0][b];
            unsigned p1 = lh[w][1][b];
            c0 += p0 >> 24; f0 += p0 & 0xFFFFFFu;
            c1 += p1 >> 24; f1 += p1 & 0xFFFFFFu;
        }
        atomicAdd(&gh[b], (c0 << 40) | f0);
        atomicAdd(&gh[NBIN + b], (c1 << 40) | f1);
    }
}

__global__ void __launch_bounds__(256) kl_kernel(const unsigned long long* __restrict__ gh,
                                                 float* __restrict__ out) {
    int i = threadIdx.x;  // exactly 256 threads, one bin each
    // unpack: h[b] = count[b] - dsum[b] + dsum[b-1]   (spill past 255 drops out)
    unsigned long long p0 = gh[i];
    unsigned long long p1 = gh[NBIN + i];
    unsigned long long q0 = (i > 0) ? gh[i - 1] : 0ull;
    unsigned long long q1 = (i > 0) ? gh[NBIN + i - 1] : 0ull;
    float h0 = (float)((double)(p0 >> 40) - (double)(p0 & DMASK) * DSCALE_INV
                       + (double)(q0 & DMASK) * DSCALE_INV);
    float h1 = (float)((double)(p1 >> 40) - (double)(p1 & DMASK) * DSCALE_INV
                       + (double)(q1 & DMASK) * DSCALE_INV);

    __shared__ float sw[4];
    int lane = i & 63, wid = i >> 6;

    float v = h0;
    for (int off = 32; off; off >>= 1) v += __shfl_xor(v, off);
    if (lane == 0) sw[wid] = v;
    __syncthreads();
    float s0 = sw[0] + sw[1] + sw[2] + sw[3];
    __syncthreads();

    v = h1;
    for (int off = 32; off; off >>= 1) v += __shfl_xor(v, off);
    if (lane == 0) sw[wid] = v;
    __syncthreads();
    float s1 = sw[0] + sw[1] + sw[2] + sw[3];
    __syncthreads();

    float a = (h0 + EPSF) / (s0 + EPSF);
    float b = (h1 + EPSF) / (s1 + EPSF);
    float tgt = logf((b + EPSF) / a);
    float inp = logf((b + EPSF) / b);
    float term = expf(tgt) * (tgt - inp);

    v = term;
    for (int off = 32; off; off >>= 1) v += __shfl_xor(v, off);
    if (lane == 0) sw[wid] = v;
    __syncthreads();
    if (i == 0) out[0] = (sw[0] + sw[1] + sw[2] + sw[3]) / (float)NBIN;
}

extern "C" void kernel_launch(void* const* d_in, const int* in_sizes, int n_in,
                              void* d_out, int out_size, void* d_ws, size_t ws_size,
                              hipStream_t stream) {
    const float* img0 = (const float*)d_in[0];
    const float* img1 = (const float*)d_in[1];
    float* out = (float*)d_out;
    unsigned* ws_min = (unsigned*)d_ws;
    unsigned long long* gh = (unsigned long long*)((char*)d_ws + 16);

    long n = (long)in_sizes[0];  // 67,108,864
    long n4 = n / 4;

    init_kernel<<<1, 256, 0, stream>>>(ws_min, gh);
    min_kernel<<<2048, 256, 0, stream>>>((const float4*)img0, n4, ws_min);
    hist_kernel<<<2048, 256, 0, stream>>>((const float4*)img0, (const float4*)img1,
                                          n4, ws_min, gh);
    kl_kernel<<<1, 256, 0, stream>>>(gh, out);
}